// Round 4
// baseline (222.761 us; speedup 1.0000x reference)
//
#include <hip/hip_runtime.h>

#define SP    65536      // 16*64*64 spatial voxels
#define DD    16
#define HH    64
#define WW    64
#define CIN   64
#define COUT  64

#define LOG2E 1.44269504f

// ws layout (fp32): q [64][SP] | k [64][SP] | v [64][SP]   (48 MB)
// round-10 lesson: bf16 STORAGE of k fails accuracy. Intermediates fp32.
// round-11: proj = bf16x3 split MFMA; q pre-scaled by LOG2E.
// round-12 LESSON: no-LDS attn -> 374MB scratch spill. LDS bounds VGPRs.
// round-13 LESSONS: (a) I-cache theory FALSIFIED - unified attn body did
// nothing (53.7->55.9). (b) merged proj REGRESSED 20->45us: 1024 blocks
// can't hide per-block latency (TLP loss). proj reverted to 3-launch form.
// round-14 (this): attn occupancy attack. Counters showed ~1.4-3 blocks/CU
// resident (VGPR 140 -> 2 blocks cap); per-block wall ~7us vs ~1.5us issue
// work = pure latency exposure. New shape: 1 float4 output/thread (was 8
// outputs), LDS halo [6][6][64] = 18.4KB (was 30KB), grid 4096 (was 2048),
// launch_bounds(256,6) -> target ~6 blocks/CU.

typedef __attribute__((ext_vector_type(8))) short bf16x8;   // 8 bf16 = 4 VGPRs
typedef __attribute__((ext_vector_type(4))) float f32x4;    // MFMA acc

__device__ __forceinline__ unsigned short f2bf(float f) {   // RNE f32->bf16
    const unsigned u = __float_as_uint(f);
    return (unsigned short)((u + 0x7FFFu + ((u >> 16) & 1u)) >> 16);
}
__device__ __forceinline__ float bf2f(unsigned short h) {
    return __uint_as_float((unsigned)h << 16);
}

// proj v2 (round-11 form, reverted): per block 64 positions x all 64 outs,
// one matrix (grid.y). K=64 in LDS once. x staged TRANSPOSED [j][c] hi/lo;
// w staged [o][c] hi/lo. A/B both pack 8 consecutive cin -> same
// k-permutation on both operands -> contraction layout-permutation-safe.
// C/D layout (HW-verified): col=lane&15, row=(lane>>4)*4+reg.
__global__ __launch_bounds__(256) void proj(const float* __restrict__ x,
                                            const float* __restrict__ wq,
                                            const float* __restrict__ wk,
                                            const float* __restrict__ wv,
                                            float* __restrict__ q,
                                            float* __restrict__ k,
                                            float* __restrict__ v) {
    __shared__ __align__(16) unsigned short xh [64][72];   // [j][c] hi, 9 KB
    __shared__ __align__(16) unsigned short xlo[64][72];   // [j][c] lo
    __shared__ __align__(16) unsigned short wh [64][72];   // [o][c] hi
    __shared__ __align__(16) unsigned short wlo[64][72];   // 36.9 KB -> 4 blk/CU

    const int t  = threadIdx.x;
    const int p0 = blockIdx.x * 64;
    const int m  = blockIdx.y;

    const float* __restrict__ wsel = (m == 0) ? wq : (m == 1) ? wk : wv;
    float* __restrict__       osel = (m == 0) ? q  : (m == 1) ? k  : v;

    // stage x[c][p0+j] -> xh/xlo[j][c], split hi/lo. Row pairs (c2, c2+1)
    // packed into one u32 LDS write (residual is exact: |x-hi| <= 2^-9|x|).
#pragma unroll
    for (int i = 0; i < 2; ++i) {
        const int f  = t + 256 * i;          // 0..511
        const int c2 = (f >> 4) * 2;
        const int jj = f & 15;
        const float4 a = *(const float4*)(x + c2 * SP + p0 + jj * 4);
        const float4 b = *(const float4*)(x + (c2 + 1) * SP + p0 + jj * 4);
        const float* af = (const float*)&a;
        const float* bf = (const float*)&b;
#pragma unroll
        for (int e = 0; e < 4; ++e) {
            const int j = jj * 4 + e;
            const unsigned short ah = f2bf(af[e]);
            const unsigned short bh = f2bf(bf[e]);
            const unsigned short al = f2bf(af[e] - bf2f(ah));
            const unsigned short bl = f2bf(bf[e] - bf2f(bh));
            *(unsigned*)&xh [j][c2] = (unsigned)ah | ((unsigned)bh << 16);
            *(unsigned*)&xlo[j][c2] = (unsigned)al | ((unsigned)bl << 16);
        }
    }
    // stage w[o][c] -> wh/wlo[o][c] (same orientation, b64 writes)
#pragma unroll
    for (int i = 0; i < 4; ++i) {
        const int f  = t + 256 * i;          // 0..1023
        const int o  = f >> 4;
        const int jj = f & 15;
        const float4 w4 = *(const float4*)(wsel + o * CIN + jj * 4);
        const float* wf = (const float*)&w4;
        unsigned short h0 = f2bf(wf[0]), h1 = f2bf(wf[1]);
        unsigned short h2 = f2bf(wf[2]), h3 = f2bf(wf[3]);
        unsigned short l0 = f2bf(wf[0] - bf2f(h0)), l1 = f2bf(wf[1] - bf2f(h1));
        unsigned short l2 = f2bf(wf[2] - bf2f(h2)), l3 = f2bf(wf[3] - bf2f(h3));
        *(uint2*)&wh [o][jj * 4] = make_uint2((unsigned)h0 | ((unsigned)h1 << 16),
                                              (unsigned)h2 | ((unsigned)h3 << 16));
        *(uint2*)&wlo[o][jj * 4] = make_uint2((unsigned)l0 | ((unsigned)l1 << 16),
                                              (unsigned)l2 | ((unsigned)l3 << 16));
    }
    __syncthreads();

    const int lane  = t & 63;
    const int wid   = t >> 6;                // wave -> 16-out slice
    const int lo16  = lane & 15;
    const int lg    = lane >> 4;             // 0..3 k-group
    const int otile = wid * 16;

    // A-fragments: w[otile+lo16][k-chunk], 8 consecutive cin, 16B aligned
    const bf16x8 Ah0 = *(const bf16x8*)&wh [otile + lo16][lg * 8];
    const bf16x8 Ah1 = *(const bf16x8*)&wh [otile + lo16][32 + lg * 8];
    const bf16x8 Al0 = *(const bf16x8*)&wlo[otile + lo16][lg * 8];
    const bf16x8 Al1 = *(const bf16x8*)&wlo[otile + lo16][32 + lg * 8];

    const float scale = (m == 0) ? LOG2E : 1.f;   // fold exp2 prescale into q

#pragma unroll
    for (int jt = 0; jt < 4; ++jt) {
        const int jr = jt * 16 + lo16;
        const bf16x8 Bh0 = *(const bf16x8*)&xh [jr][lg * 8];
        const bf16x8 Bl0 = *(const bf16x8*)&xlo[jr][lg * 8];
        const bf16x8 Bh1 = *(const bf16x8*)&xh [jr][32 + lg * 8];
        const bf16x8 Bl1 = *(const bf16x8*)&xlo[jr][32 + lg * 8];
        f32x4 hh = {0.f, 0.f, 0.f, 0.f};     // 3 independent chains for ILP
        f32x4 hl = {0.f, 0.f, 0.f, 0.f};
        f32x4 lh = {0.f, 0.f, 0.f, 0.f};
        hh = __builtin_amdgcn_mfma_f32_16x16x32_bf16(Ah0, Bh0, hh, 0, 0, 0);
        hl = __builtin_amdgcn_mfma_f32_16x16x32_bf16(Ah0, Bl0, hl, 0, 0, 0);
        lh = __builtin_amdgcn_mfma_f32_16x16x32_bf16(Al0, Bh0, lh, 0, 0, 0);
        hh = __builtin_amdgcn_mfma_f32_16x16x32_bf16(Ah1, Bh1, hh, 0, 0, 0);
        hl = __builtin_amdgcn_mfma_f32_16x16x32_bf16(Ah1, Bl1, hl, 0, 0, 0);
        lh = __builtin_amdgcn_mfma_f32_16x16x32_bf16(Al1, Bh1, lh, 0, 0, 0);
        float* op = osel + (otile + lg * 4) * SP + p0 + jt * 16 + lo16;
#pragma unroll
        for (int r = 0; r < 4; ++r)
            op[r * SP] = (hh[r] + hl[r] + lh[r]) * scale;   // 4 rows x 64B, coalesced
    }
}

// DPP shifts within 16-lane rows; bound_ctrl=1 -> out-of-row reads 0 =
// exactly the w-boundary zero-pad (wg==0/15 are DPP row boundaries).
__device__ __forceinline__ float dpp_shr1(float x) {   // lane i <- lane i-1
    return __int_as_float(__builtin_amdgcn_mov_dpp(__float_as_int(x), 0x111, 0xf, 0xf, true));
}
__device__ __forceinline__ float dpp_shl1(float x) {   // lane i <- lane i+1
    return __int_as_float(__builtin_amdgcn_mov_dpp(__float_as_int(x), 0x101, 0xf, 0xf, true));
}

// attn v6: block = (dtile4 x htile4, o) -> 4d x 4h x 64w outputs of one
// channel; thread = ONE float4 (1d x 4w). LDS halo [6][6][64] k+v = 18.4KB.
// 27 rel combos in SGPRs (readfirstlane, constant-indexed). Single-pass
// softmax; OOB: k=0+rel in softmax, v=0.
__global__ __launch_bounds__(256, 6) void attn(const float* __restrict__ kbuf,
                                               const float* __restrict__ vbuf,
                                               const float* __restrict__ qbuf,
                                               const float* __restrict__ rel_d,
                                               const float* __restrict__ rel_h,
                                               const float* __restrict__ rel_w,
                                               float* __restrict__ out) {
    __shared__ float kt[36 * 64];    // [nd][nh][w], 9.2 KB
    __shared__ float vt[36 * 64];

    const int dt = blockIdx.x;       // 0..3
    const int ht = blockIdx.y;       // 0..15
    const int o  = blockIdx.z;       // 0..63

    const int d0 = dt * 4;
    const int h0 = ht * 4;
    const int t  = threadIdx.x;

    const float* __restrict__ kc = kbuf + o * SP;
    const float* __restrict__ vc = vbuf + o * SP;

    // stage k,v halo tiles: 2 * 36 rows * 16 float4 = 1152 float4
#pragma unroll
    for (int i = 0; i < 5; ++i) {
        const int idx = t + 256 * i;
        if (idx < 1152) {
            const bool isv = idx >= 576;
            const int rem  = isv ? idx - 576 : idx;
            const int row  = rem >> 4;         // 0..35
            const int j    = rem & 15;
            const int nd   = row / 6;
            const int nh   = row - nd * 6;
            const int dpg  = d0 - 1 + nd;
            const int hpg  = h0 - 1 + nh;
            float4 val = make_float4(0.f, 0.f, 0.f, 0.f);
            if ((unsigned)dpg < (unsigned)DD && (unsigned)hpg < (unsigned)HH) {
                const float* src = (isv ? vc : kc) + (dpg * HH + hpg) * WW + j * 4;
                val = *(const float4*)src;
            }
            *(float4*)((isv ? vt : kt) + row * 64 + j * 4) = val;
        }
    }

    // unified rel table: 27 combos -> SGPRs (overlaps with staging latency)
    float ra0, ra1, ra2;
    int ax;
    if (o < 21)      { ax = 0; ra0 = rel_d[o * 3]; ra1 = rel_d[o * 3 + 1]; ra2 = rel_d[o * 3 + 2]; }
    else if (o < 42) { ax = 1; const int b = o - 21;
                       ra0 = rel_h[b * 3]; ra1 = rel_h[b * 3 + 1]; ra2 = rel_h[b * 3 + 2]; }
    else             { ax = 2; const int b = o - 42;
                       ra0 = rel_w[b * 3]; ra1 = rel_w[b * 3 + 1]; ra2 = rel_w[b * 3 + 2]; }
    float R[27];
#pragma unroll
    for (int kd = 0; kd < 3; ++kd)
#pragma unroll
        for (int kh = 0; kh < 3; ++kh)
#pragma unroll
            for (int kw = 0; kw < 3; ++kw) {
                const float vd = (kd == 0) ? ra0 : (kd == 1) ? ra1 : ra2;
                const float vh = (kh == 0) ? ra0 : (kh == 1) ? ra1 : ra2;
                const float vw = (kw == 0) ? ra0 : (kw == 1) ? ra1 : ra2;
                const float rv = (ax == 0) ? vd : (ax == 1) ? vh : vw;
                R[kd * 9 + kh * 3 + kw] =
                    __uint_as_float(__builtin_amdgcn_readfirstlane(__float_as_uint(rv)));
            }

    const int wg = t & 15;           // float4 in w
    const int hl = (t >> 4) & 3;     // local h
    const int dl = t >> 6;           // local d (== wave id)

    const int dabs = d0 + dl;
    const int habs = h0 + hl;

    float ql[4];
    {
        const float4 q4 = *(const float4*)(qbuf + o * SP + (dabs * HH + habs) * WW + wg * 4);
        ql[0] = q4.x; ql[1] = q4.y;            // q pre-scaled by LOG2E in proj
        ql[2] = q4.z; ql[3] = q4.w;
    }

    __syncthreads();

    float s[4] = {};
    float a[4] = {};

#pragma unroll
    for (int kd = 0; kd < 3; ++kd) {
#pragma unroll
        for (int kh = 0; kh < 3; ++kh) {
            const int off = ((dl + kd) * 6 + hl + kh) * 64 + wg * 4;
            const float4 km = *(const float4*)(kt + off);
            const float4 vm = *(const float4*)(vt + off);
            const float kl = dpp_shr1(km.w), kr = dpp_shl1(km.x);
            const float vl = dpp_shr1(vm.w), vr = dpp_shl1(vm.x);
            const float krow[6] = { kl, km.x, km.y, km.z, km.w, kr };
            const float vrow[6] = { vl, vm.x, vm.y, vm.z, vm.w, vr };
#pragma unroll
            for (int wi = 0; wi < 4; ++wi) {
                const float qv = ql[wi];
#pragma unroll
                for (int kw = 0; kw < 3; ++kw) {
                    const float rc = R[kd * 9 + kh * 3 + kw];  // SGPR, const idx
                    const float e = __builtin_amdgcn_exp2f(qv * (krow[wi + kw] + rc));
                    s[wi] += e;
                    a[wi] = fmaf(e, vrow[wi + kw], a[wi]);
                }
            }
        }
    }

    float4 ov;
    ov.x = a[0] * __builtin_amdgcn_rcpf(s[0]);
    ov.y = a[1] * __builtin_amdgcn_rcpf(s[1]);
    ov.z = a[2] * __builtin_amdgcn_rcpf(s[2]);
    ov.w = a[3] * __builtin_amdgcn_rcpf(s[3]);
    *(float4*)(out + o * SP + (dabs * HH + habs) * WW + wg * 4) = ov;
}

extern "C" void kernel_launch(void* const* d_in, const int* in_sizes, int n_in,
                              void* d_out, int out_size, void* d_ws, size_t ws_size,
                              hipStream_t stream) {
    const float* x     = (const float*)d_in[0];
    const float* w_q   = (const float*)d_in[1];
    const float* w_k   = (const float*)d_in[2];
    const float* w_v   = (const float*)d_in[3];
    const float* rel_d = (const float*)d_in[4];
    const float* rel_h = (const float*)d_in[5];
    const float* rel_w = (const float*)d_in[6];
    float* out = (float*)d_out;

    float* ws = (float*)d_ws;
    float* q  = ws;
    float* k  = ws + (size_t)COUT * SP;
    float* v  = ws + 2 * (size_t)COUT * SP;

    proj<<<dim3(SP / 64, 3), 256, 0, stream>>>(x, w_q, w_k, w_v, q, k, v);
    attn<<<dim3(4, 16, 64), 256, 0, stream>>>(k, v, q, rel_d, rel_h, rel_w, out);
}

// Round 5
// 118.901 us; speedup vs baseline: 1.8735x; 1.8735x over previous
//
#include <hip/hip_runtime.h>

#define SP    65536      // 16*64*64 spatial voxels
#define DD    16
#define HH    64
#define WW    64
#define CIN   64
#define COUT  64

#define RP    68         // attn LDS row pitch (floats): 272B -> 4-bank shift/row

#define LOG2E 1.44269504f

// ws layout (fp32): q [64][SP] | k [64][SP] | v [64][SP]   (48 MB)
// round-10 lesson: bf16 STORAGE of k fails accuracy. Intermediates fp32.
// round-11: proj = bf16x3 split MFMA; q pre-scaled by LOG2E.
// round-12 LESSON: no-LDS attn -> 374MB scratch spill. LDS bounds VGPRs.
// round-13 LESSONS: (a) I-cache theory FALSIFIED. (b) merged proj regressed
// (TLP loss); 3-launch proj kept.
// round-14 LESSON: launch_bounds(256,6) forced allocator to <=85 VGPR ->
// R[27]+state spilled to scratch (WRITE 424MB, VGPR=40). The SHAPE was right
// (occupancy 59% even while spilling). Never pair min-waves pressure with
// per-thread array state.
// round-15 (this): v6 shape kept (1 float4/thread, 4096 blocks), but:
// no min-waves bound, template<AXIS> w/ 3 scalars (no R[27]), LDS pitch 68
// (was 64) to break the 4-way row-alias bank conflict.

typedef __attribute__((ext_vector_type(8))) short bf16x8;   // 8 bf16 = 4 VGPRs
typedef __attribute__((ext_vector_type(4))) float f32x4;    // MFMA acc

__device__ __forceinline__ unsigned short f2bf(float f) {   // RNE f32->bf16
    const unsigned u = __float_as_uint(f);
    return (unsigned short)((u + 0x7FFFu + ((u >> 16) & 1u)) >> 16);
}
__device__ __forceinline__ float bf2f(unsigned short h) {
    return __uint_as_float((unsigned)h << 16);
}

// proj v2 (round-11 form, known-good ~20us): per block 64 positions x all
// 64 outs, one matrix (grid.y). K=64 in LDS once. x staged TRANSPOSED
// [j][c] hi/lo; w staged [o][c] hi/lo. A/B both pack 8 consecutive cin ->
// same k-permutation on both operands -> contraction layout-safe.
// C/D layout (HW-verified): col=lane&15, row=(lane>>4)*4+reg.
__global__ __launch_bounds__(256) void proj(const float* __restrict__ x,
                                            const float* __restrict__ wq,
                                            const float* __restrict__ wk,
                                            const float* __restrict__ wv,
                                            float* __restrict__ q,
                                            float* __restrict__ k,
                                            float* __restrict__ v) {
    __shared__ __align__(16) unsigned short xh [64][72];   // [j][c] hi, 9 KB
    __shared__ __align__(16) unsigned short xlo[64][72];   // [j][c] lo
    __shared__ __align__(16) unsigned short wh [64][72];   // [o][c] hi
    __shared__ __align__(16) unsigned short wlo[64][72];   // 36.9 KB -> 4 blk/CU

    const int t  = threadIdx.x;
    const int p0 = blockIdx.x * 64;
    const int m  = blockIdx.y;

    const float* __restrict__ wsel = (m == 0) ? wq : (m == 1) ? wk : wv;
    float* __restrict__       osel = (m == 0) ? q  : (m == 1) ? k  : v;

    // stage x[c][p0+j] -> xh/xlo[j][c], split hi/lo. Row pairs (c2, c2+1)
    // packed into one u32 LDS write (residual is exact: |x-hi| <= 2^-9|x|).
#pragma unroll
    for (int i = 0; i < 2; ++i) {
        const int f  = t + 256 * i;          // 0..511
        const int c2 = (f >> 4) * 2;
        const int jj = f & 15;
        const float4 a = *(const float4*)(x + c2 * SP + p0 + jj * 4);
        const float4 b = *(const float4*)(x + (c2 + 1) * SP + p0 + jj * 4);
        const float* af = (const float*)&a;
        const float* bf = (const float*)&b;
#pragma unroll
        for (int e = 0; e < 4; ++e) {
            const int j = jj * 4 + e;
            const unsigned short ah = f2bf(af[e]);
            const unsigned short bh = f2bf(bf[e]);
            const unsigned short al = f2bf(af[e] - bf2f(ah));
            const unsigned short bl = f2bf(bf[e] - bf2f(bh));
            *(unsigned*)&xh [j][c2] = (unsigned)ah | ((unsigned)bh << 16);
            *(unsigned*)&xlo[j][c2] = (unsigned)al | ((unsigned)bl << 16);
        }
    }
    // stage w[o][c] -> wh/wlo[o][c] (same orientation, b64 writes)
#pragma unroll
    for (int i = 0; i < 4; ++i) {
        const int f  = t + 256 * i;          // 0..1023
        const int o  = f >> 4;
        const int jj = f & 15;
        const float4 w4 = *(const float4*)(wsel + o * CIN + jj * 4);
        const float* wf = (const float*)&w4;
        unsigned short h0 = f2bf(wf[0]), h1 = f2bf(wf[1]);
        unsigned short h2 = f2bf(wf[2]), h3 = f2bf(wf[3]);
        unsigned short l0 = f2bf(wf[0] - bf2f(h0)), l1 = f2bf(wf[1] - bf2f(h1));
        unsigned short l2 = f2bf(wf[2] - bf2f(h2)), l3 = f2bf(wf[3] - bf2f(h3));
        *(uint2*)&wh [o][jj * 4] = make_uint2((unsigned)h0 | ((unsigned)h1 << 16),
                                              (unsigned)h2 | ((unsigned)h3 << 16));
        *(uint2*)&wlo[o][jj * 4] = make_uint2((unsigned)l0 | ((unsigned)l1 << 16),
                                              (unsigned)l2 | ((unsigned)l3 << 16));
    }
    __syncthreads();

    const int lane  = t & 63;
    const int wid   = t >> 6;                // wave -> 16-out slice
    const int lo16  = lane & 15;
    const int lg    = lane >> 4;             // 0..3 k-group
    const int otile = wid * 16;

    // A-fragments: w[otile+lo16][k-chunk], 8 consecutive cin, 16B aligned
    const bf16x8 Ah0 = *(const bf16x8*)&wh [otile + lo16][lg * 8];
    const bf16x8 Ah1 = *(const bf16x8*)&wh [otile + lo16][32 + lg * 8];
    const bf16x8 Al0 = *(const bf16x8*)&wlo[otile + lo16][lg * 8];
    const bf16x8 Al1 = *(const bf16x8*)&wlo[otile + lo16][32 + lg * 8];

    const float scale = (m == 0) ? LOG2E : 1.f;   // fold exp2 prescale into q

#pragma unroll
    for (int jt = 0; jt < 4; ++jt) {
        const int jr = jt * 16 + lo16;
        const bf16x8 Bh0 = *(const bf16x8*)&xh [jr][lg * 8];
        const bf16x8 Bl0 = *(const bf16x8*)&xlo[jr][lg * 8];
        const bf16x8 Bh1 = *(const bf16x8*)&xh [jr][32 + lg * 8];
        const bf16x8 Bl1 = *(const bf16x8*)&xlo[jr][32 + lg * 8];
        f32x4 hh = {0.f, 0.f, 0.f, 0.f};     // 3 independent chains for ILP
        f32x4 hl = {0.f, 0.f, 0.f, 0.f};
        f32x4 lh = {0.f, 0.f, 0.f, 0.f};
        hh = __builtin_amdgcn_mfma_f32_16x16x32_bf16(Ah0, Bh0, hh, 0, 0, 0);
        hl = __builtin_amdgcn_mfma_f32_16x16x32_bf16(Ah0, Bl0, hl, 0, 0, 0);
        lh = __builtin_amdgcn_mfma_f32_16x16x32_bf16(Al0, Bh0, lh, 0, 0, 0);
        hh = __builtin_amdgcn_mfma_f32_16x16x32_bf16(Ah1, Bh1, hh, 0, 0, 0);
        hl = __builtin_amdgcn_mfma_f32_16x16x32_bf16(Ah1, Bl1, hl, 0, 0, 0);
        lh = __builtin_amdgcn_mfma_f32_16x16x32_bf16(Al1, Bh1, lh, 0, 0, 0);
        float* op = osel + (otile + lg * 4) * SP + p0 + jt * 16 + lo16;
#pragma unroll
        for (int r = 0; r < 4; ++r)
            op[r * SP] = (hh[r] + hl[r] + lh[r]) * scale;   // 4 rows x 64B, coalesced
    }
}

// DPP shifts within 16-lane rows; bound_ctrl=1 -> out-of-row reads 0 =
// exactly the w-boundary zero-pad (wg==0/15 are DPP row boundaries).
__device__ __forceinline__ float dpp_shr1(float x) {   // lane i <- lane i-1
    return __int_as_float(__builtin_amdgcn_mov_dpp(__float_as_int(x), 0x111, 0xf, 0xf, true));
}
__device__ __forceinline__ float dpp_shl1(float x) {   // lane i <- lane i+1
    return __int_as_float(__builtin_amdgcn_mov_dpp(__float_as_int(x), 0x101, 0xf, 0xf, true));
}

// attn v7 walk: thread = 1 float4 output; 9 (kd,kh) rows, 3 rel scalars.
template<int AXIS>
__device__ __forceinline__ void attn_walk(const float* __restrict__ kt,
                                          const float* __restrict__ vt,
                                          const float (&ql)[4],
                                          float r0, float r1, float r2,
                                          int wg, int hl, int dl,
                                          float (&s)[4], float (&a)[4]) {
#pragma unroll
    for (int kd = 0; kd < 3; ++kd) {
        const float rdd = (kd == 0) ? r0 : (kd == 1) ? r1 : r2;
#pragma unroll
        for (int kh = 0; kh < 3; ++kh) {
            const float rkh = (kh == 0) ? r0 : (kh == 1) ? r1 : r2;
            const float rr  = (AXIS == 0) ? rdd : (AXIS == 1) ? rkh : 0.f;
            const int off = ((dl + kd) * 6 + hl + kh) * RP + wg * 4;
            const float4 km = *(const float4*)(kt + off);
            const float4 vm = *(const float4*)(vt + off);
            const float kl = dpp_shr1(km.w), kr = dpp_shl1(km.x);
            const float vl = dpp_shr1(vm.w), vr = dpp_shl1(vm.x);
            const float krow[6] = { kl, km.x, km.y, km.z, km.w, kr };
            const float vrow[6] = { vl, vm.x, vm.y, vm.z, vm.w, vr };
#pragma unroll
            for (int wi = 0; wi < 4; ++wi) {
                const float qv = ql[wi];
#pragma unroll
                for (int kw = 0; kw < 3; ++kw) {
                    const float rc = (AXIS == 2)
                                   ? ((kw == 0) ? r0 : (kw == 1) ? r1 : r2)
                                   : rr;
                    const float e = __builtin_amdgcn_exp2f(qv * (krow[wi + kw] + rc));
                    s[wi] += e;
                    a[wi] = fmaf(e, vrow[wi + kw], a[wi]);
                }
            }
        }
    }
}

// attn v7: block = (dtile4 x htile4, o) -> 4d x 4h x 64w outputs of one
// channel; thread = ONE float4 (1d x 4w). LDS halo [6][6][RP] k+v = 19.6KB
// -> 8 blocks/CU by LDS. No min-waves bound (round-14 lesson). Single-pass
// softmax; OOB: k=0+rel in softmax, v=0.
__global__ __launch_bounds__(256) void attn(const float* __restrict__ kbuf,
                                            const float* __restrict__ vbuf,
                                            const float* __restrict__ qbuf,
                                            const float* __restrict__ rel_d,
                                            const float* __restrict__ rel_h,
                                            const float* __restrict__ rel_w,
                                            float* __restrict__ out) {
    __shared__ float kt[36 * RP];    // [nd][nh][w], 9.8 KB
    __shared__ float vt[36 * RP];

    const int dt = blockIdx.x;       // 0..3
    const int ht = blockIdx.y;       // 0..15
    const int o  = blockIdx.z;       // 0..63

    const int d0 = dt * 4;
    const int h0 = ht * 4;
    const int t  = threadIdx.x;

    const float* __restrict__ kc = kbuf + o * SP;
    const float* __restrict__ vc = vbuf + o * SP;

    // stage k,v halo tiles: 2 * 36 rows * 16 float4 = 1152 float4
#pragma unroll
    for (int i = 0; i < 5; ++i) {
        const int idx = t + 256 * i;
        if (idx < 1152) {
            const bool isv = idx >= 576;
            const int rem  = isv ? idx - 576 : idx;
            const int row  = rem >> 4;         // 0..35
            const int j    = rem & 15;
            const int nd   = row / 6;
            const int nh   = row - nd * 6;
            const int dpg  = d0 - 1 + nd;
            const int hpg  = h0 - 1 + nh;
            float4 val = make_float4(0.f, 0.f, 0.f, 0.f);
            if ((unsigned)dpg < (unsigned)DD && (unsigned)hpg < (unsigned)HH) {
                const float* src = (isv ? vc : kc) + (dpg * HH + hpg) * WW + j * 4;
                val = *(const float4*)src;
            }
            *(float4*)((isv ? vt : kt) + row * RP + j * 4) = val;
        }
    }

    const int wg = t & 15;           // float4 in w
    const int hl = (t >> 4) & 3;     // local h
    const int dl = t >> 6;           // local d (== wave id)

    const int dabs = d0 + dl;
    const int habs = h0 + hl;

    float ql[4];
    {
        const float4 q4 = *(const float4*)(qbuf + o * SP + (dabs * HH + habs) * WW + wg * 4);
        ql[0] = q4.x; ql[1] = q4.y;            // q pre-scaled by LOG2E in proj
        ql[2] = q4.z; ql[3] = q4.w;
    }

    __syncthreads();

    float s[4] = {};
    float a[4] = {};

    if (o < 21) {
        attn_walk<0>(kt, vt, ql, rel_d[o * 3], rel_d[o * 3 + 1], rel_d[o * 3 + 2],
                     wg, hl, dl, s, a);
    } else if (o < 42) {
        const int b = o - 21;
        attn_walk<1>(kt, vt, ql, rel_h[b * 3], rel_h[b * 3 + 1], rel_h[b * 3 + 2],
                     wg, hl, dl, s, a);
    } else {
        const int b = o - 42;
        attn_walk<2>(kt, vt, ql, rel_w[b * 3], rel_w[b * 3 + 1], rel_w[b * 3 + 2],
                     wg, hl, dl, s, a);
    }

    float4 ov;
    ov.x = a[0] * __builtin_amdgcn_rcpf(s[0]);
    ov.y = a[1] * __builtin_amdgcn_rcpf(s[1]);
    ov.z = a[2] * __builtin_amdgcn_rcpf(s[2]);
    ov.w = a[3] * __builtin_amdgcn_rcpf(s[3]);
    *(float4*)(out + o * SP + (dabs * HH + habs) * WW + wg * 4) = ov;
}

extern "C" void kernel_launch(void* const* d_in, const int* in_sizes, int n_in,
                              void* d_out, int out_size, void* d_ws, size_t ws_size,
                              hipStream_t stream) {
    const float* x     = (const float*)d_in[0];
    const float* w_q   = (const float*)d_in[1];
    const float* w_k   = (const float*)d_in[2];
    const float* w_v   = (const float*)d_in[3];
    const float* rel_d = (const float*)d_in[4];
    const float* rel_h = (const float*)d_in[5];
    const float* rel_w = (const float*)d_in[6];
    float* out = (float*)d_out;

    float* ws = (float*)d_ws;
    float* q  = ws;
    float* k  = ws + (size_t)COUT * SP;
    float* v  = ws + 2 * (size_t)COUT * SP;

    proj<<<dim3(SP / 64, 3), 256, 0, stream>>>(x, w_q, w_k, w_v, q, k, v);
    attn<<<dim3(4, 16, 64), 256, 0, stream>>>(k, v, q, rel_d, rel_h, rel_w, out);
}